// Round 2
// baseline (3822.062 us; speedup 1.0000x reference)
//
#include <hip/hip_runtime.h>

typedef unsigned short u16;
typedef unsigned int   u32;

#define DEV static __device__ __forceinline__

constexpr int S   = 2048;
constexpr int D   = 1024;
constexpr int H   = 16;
constexpr int BB  = 8;
constexpr int BH  = BB * H;        // 128
constexpr int BS  = BB * S;        // 16384 (b,s) rows
constexpr long NR = (long)BH * S;  // 262144 (bh,s) rows
constexpr int GB  = 32;            // bh per group
constexpr int NG  = BH / GB;       // 4 groups

DEV float b2f(u16 u) { return __uint_as_float(((u32)u) << 16); }
DEV u16   f2b(float f) {
  u32 x = __float_as_uint(f);
  u32 r = (x + 0x7fffu + ((x >> 16) & 1u)) >> 16;
  return (u16)r;
}
DEV float geluf(float x) { return 0.5f * x * (1.0f + erff(x * 0.70710678118654752440f)); }
DEV float gelu_gradf(float x) {
  float cdf = 0.5f * (1.0f + erff(x * 0.70710678118654752440f));
  float pdf = expf(-0.5f * x * x) * 0.3989422804014327f;
  return cdf + x * pdf;
}
DEV float sigmoidf(float z) { return 1.0f / (1.0f + expf(-z)); }
DEV float wsum(float v) {
#pragma unroll
  for (int o = 32; o > 0; o >>= 1) v += __shfl_xor(v, o, 64);
  return v;
}
DEV float nan0(float v) {
  u32 b = __float_as_uint(v);
  return ((b & 0x7f800000u) == 0x7f800000u) ? 0.f : v;
}
DEV bool finitef(float v) {
  u32 b = __float_as_uint(v);
  return (b & 0x7f800000u) != 0x7f800000u;
}

// 16-step k inner product on staged LDS tiles (64x64 tile, 4x4 per thread)
#define GEMM_INNER16                                        \
  _Pragma("unroll")                                         \
  for (int kk = 0; kk < 16; kk++) {                         \
    float4 a4 = *(const float4*)&As[kk][tm << 2];           \
    float4 b4 = *(const float4*)&Bs[kk][tn << 2];           \
    float aa[4] = {a4.x, a4.y, a4.z, a4.w};                 \
    float bb[4] = {b4.x, b4.y, b4.z, b4.w};                 \
    _Pragma("unroll") for (int ii = 0; ii < 4; ii++)        \
      _Pragma("unroll") for (int jj = 0; jj < 4; jj++)      \
        acc[ii][jj] += aa[ii] * bb[jj];                     \
  }

// ---------------- per-(b,s)-row rms of x over D=1024 ----------------
__global__ void k_rowrms(const float* __restrict__ x, float* __restrict__ rinv) {
  int row  = blockIdx.x * 4 + (threadIdx.x >> 6);
  int lane = threadIdx.x & 63;
  const float* p = x + (size_t)row * D;
  float s = 0.f;
#pragma unroll
  for (int j = 0; j < 4; j++) {
    float4 v = *(const float4*)(p + lane * 4 + j * 256);
    s += v.x * v.x + v.y * v.y + v.z * v.z + v.w * v.w;
  }
  s = wsum(s);
  if (lane == 0) rinv[row] = rsqrtf(s * (1.0f / D) + 1e-6f);
}

// ---- projection GEMM (16384x1024 @ 1024x1024) fused with head-split (+norm) ----
// Block tile: 64 token-rows x 64 cols (= exactly head blockIdx.x).
// Output: bf16 (BH, S, 64) layout.
template <bool NORM>
__global__ __launch_bounds__(256) void k_proj(
    const float* __restrict__ A, const float* __restrict__ W,
    const float* __restrict__ rinv, const float* __restrict__ colw,
    const float* __restrict__ hw, u16* __restrict__ out) {
  __shared__ float As[16][68];
  __shared__ float Bs[16][68];
  __shared__ float Cs[64][72];
  __shared__ float wsm[64];
  int t = threadIdx.x;
  int h = blockIdx.x;
  int n0 = h * 64, row0 = blockIdx.y * 64;
  if (NORM && t < 64) wsm[t] = hw[t];
  int am = t >> 2, ak = (t & 3) << 2;
  int bk = t >> 4, bn = (t & 15) << 2;
  int tm = t & 15, tn = t >> 4;
  float rsc = rinv[row0 + am];
  float acc[4][4] = {};
  for (int k0 = 0; k0 < D; k0 += 16) {
    float4 av = *(const float4*)(A + (size_t)(row0 + am) * D + k0 + ak);
    float4 cw = *(const float4*)(colw + k0 + ak);
    As[ak + 0][am] = av.x * rsc * cw.x;
    As[ak + 1][am] = av.y * rsc * cw.y;
    As[ak + 2][am] = av.z * rsc * cw.z;
    As[ak + 3][am] = av.w * rsc * cw.w;
    *(float4*)&Bs[bk][bn] = *(const float4*)(W + (size_t)(k0 + bk) * D + n0 + bn);
    __syncthreads();
    GEMM_INNER16
    __syncthreads();
  }
  if (!NORM) {
#pragma unroll
    for (int ii = 0; ii < 4; ii++) {
      int gr = row0 + tm * 4 + ii;
      int b = gr >> 11, s_ = gr & 2047;
      ushort4 o;
      o.x = f2b(acc[ii][0]); o.y = f2b(acc[ii][1]);
      o.z = f2b(acc[ii][2]); o.w = f2b(acc[ii][3]);
      *(ushort4*)&out[((long)(b * 16 + h) * S + s_) * 64 + tn * 4] = o;
    }
  } else {
#pragma unroll
    for (int ii = 0; ii < 4; ii++)
#pragma unroll
      for (int jj = 0; jj < 4; jj++)
        Cs[tm * 4 + ii][tn * 4 + jj] = acc[ii][jj];
    __syncthreads();
    int row = t >> 2, qd = t & 3;
    float hv[16];
    float ss = 0.f;
#pragma unroll
    for (int j4 = 0; j4 < 4; j4++) {
      float4 v = *(const float4*)&Cs[row][qd * 16 + j4 * 4];
      hv[j4 * 4 + 0] = v.x; hv[j4 * 4 + 1] = v.y;
      hv[j4 * 4 + 2] = v.z; hv[j4 * 4 + 3] = v.w;
      ss += v.x * v.x + v.y * v.y + v.z * v.z + v.w * v.w;
    }
    ss += __shfl_xor(ss, 1, 64);
    ss += __shfl_xor(ss, 2, 64);
    float rn = rsqrtf(ss * (1.f / 64) + 1e-6f);
    int gr = row0 + row;
    int b = gr >> 11, s_ = gr & 2047;
    long base = ((long)(b * 16 + h) * S + s_) * 64 + qd * 16;
#pragma unroll
    for (int j4 = 0; j4 < 4; j4++) {
      ushort4 o;
      o.x = f2b(hv[j4 * 4 + 0] * rn * wsm[qd * 16 + j4 * 4 + 0]);
      o.y = f2b(hv[j4 * 4 + 1] * rn * wsm[qd * 16 + j4 * 4 + 1]);
      o.z = f2b(hv[j4 * 4 + 2] * rn * wsm[qd * 16 + j4 * 4 + 2]);
      o.w = f2b(hv[j4 * 4 + 3] * rn * wsm[qd * 16 + j4 * 4 + 3]);
      *(ushort4*)&out[base + j4 * 4] = o;
    }
  }
}

// ---------------- alpha / theta: sigmoid(x_n @ [aw|tw] + bias) ----------------
__global__ __launch_bounds__(256) void k_ate(
    const float* __restrict__ x, const float* __restrict__ rinv, const float* __restrict__ snw,
    const float* __restrict__ aw, const float* __restrict__ ab,
    const float* __restrict__ tw, const float* __restrict__ tb,
    float* __restrict__ alpha, float* __restrict__ theta) {
  __shared__ float As[16][68];
  __shared__ float Ws[16][32];
  int t = threadIdx.x;
  int row0 = blockIdx.x * 64;
  int am = t >> 2, ak = (t & 3) << 2;
  float rsc = rinv[row0 + am];
  int m = t & 63, c0 = (t >> 6) * 8;
  float acc[8] = {};
  for (int k0 = 0; k0 < D; k0 += 16) {
    float4 av = *(const float4*)(x + (size_t)(row0 + am) * D + k0 + ak);
    float4 cw = *(const float4*)(snw + k0 + ak);
    As[ak + 0][am] = av.x * rsc * cw.x;
    As[ak + 1][am] = av.y * rsc * cw.y;
    As[ak + 2][am] = av.z * rsc * cw.z;
    As[ak + 3][am] = av.w * rsc * cw.w;
#pragma unroll
    for (int j = 0; j < 2; j++) {
      int idx = t * 2 + j;
      int kk = idx >> 5, c = idx & 31;
      Ws[kk][c] = (c < 16) ? aw[(size_t)(k0 + kk) * 16 + c]
                           : tw[(size_t)(k0 + kk) * 16 + (c - 16)];
    }
    __syncthreads();
#pragma unroll
    for (int kk = 0; kk < 16; kk++) {
      float a = As[kk][m];
#pragma unroll
      for (int j = 0; j < 8; j++) acc[j] += a * Ws[kk][c0 + j];
    }
    __syncthreads();
  }
  int r = row0 + m;
  int b = r >> 11, s_ = r & 2047;
#pragma unroll
  for (int j = 0; j < 8; j++) {
    int c = c0 + j;
    int g = c >> 4, hh = c & 15;
    float bias = g ? tb[hh] : ab[hh];
    float v = sigmoidf(acc[j] + bias);
    if (g) v *= 0.01f;  // MAX_LR
    float* dst = g ? theta : alpha;
    dst[(long)(b * 16 + hh) * S + s_] = v;
  }
}

// ---------------- per-bh mean of alpha ----------------
__global__ void k_mean(const float* __restrict__ alpha, float* __restrict__ amean) {
  int bh = blockIdx.x, t = threadIdx.x;
  float sa = 0.f;
  for (int i = t; i < S; i += 256) sa += alpha[(long)bh * S + i];
  sa = wsum(sa);
  __shared__ float sh[4];
  int w = t >> 6, lane = t & 63;
  if (lane == 0) sh[w] = sa;
  __syncthreads();
  if (t == 0) amean[bh] = (sh[0] + sh[1] + sh[2] + sh[3]) * (1.f / S);
}

// -------- K=64 GEMM: rows x 64 @ 64x256 -> bf16 (row-stride 256) --------
// MODE 0: A=bf16 (keys or q), out raw (pre0)
// MODE 1: A=f32 (dh), out = (dh @ W1t) * gelu'(aux=pre0)
template <int MODE>
__global__ __launch_bounds__(256) void k64(
    const u16* __restrict__ Ab, const float* __restrict__ Af,
    const float* __restrict__ Bmat, long bstride,
    const u16* __restrict__ aux, u16* __restrict__ out) {
  __shared__ float As[16][68];
  __shared__ float Bs[16][68];
  int t = threadIdx.x;
  int n0 = blockIdx.x * 64;
  long rowbase = (long)blockIdx.z * S + (long)blockIdx.y * 64;
  const float* Bp = Bmat + (long)blockIdx.z * bstride;
  int am = t >> 2, ak = (t & 3) << 2;
  int bk = t >> 4, bn = (t & 15) << 2;
  int tm = t & 15, tn = t >> 4;
  float acc[4][4] = {};
  for (int k0 = 0; k0 < 64; k0 += 16) {
    long ar = rowbase + am;
    if (MODE == 1) {
      float4 av = *(const float4*)(Af + ar * 64 + k0 + ak);
      As[ak + 0][am] = av.x; As[ak + 1][am] = av.y;
      As[ak + 2][am] = av.z; As[ak + 3][am] = av.w;
    } else {
      ushort4 av = *(const ushort4*)(Ab + ar * 64 + k0 + ak);
      As[ak + 0][am] = b2f(av.x); As[ak + 1][am] = b2f(av.y);
      As[ak + 2][am] = b2f(av.z); As[ak + 3][am] = b2f(av.w);
    }
    *(float4*)&Bs[bk][bn] = *(const float4*)(Bp + (size_t)(k0 + bk) * 256 + n0 + bn);
    __syncthreads();
    GEMM_INNER16
    __syncthreads();
  }
#pragma unroll
  for (int ii = 0; ii < 4; ii++) {
    long r = rowbase + tm * 4 + ii;
    int c0 = n0 + tn * 4;
    float v[4] = {acc[ii][0], acc[ii][1], acc[ii][2], acc[ii][3]};
    if (MODE == 1) {
      ushort4 a4 = *(const ushort4*)&aux[r * 256 + c0];
      v[0] *= gelu_gradf(b2f(a4.x)); v[1] *= gelu_gradf(b2f(a4.y));
      v[2] *= gelu_gradf(b2f(a4.z)); v[3] *= gelu_gradf(b2f(a4.w));
    }
    ushort4 o;
    o.x = f2b(v[0]); o.y = f2b(v[1]); o.z = f2b(v[2]); o.w = f2b(v[3]);
    *(ushort4*)&out[r * 256 + c0] = o;
  }
}

// -------- K=256 GEMM: rows x 256 (gelu on A) @ 256x64, fused epilogue --------
// MODE 0: grad path  -> rowgrad epilogue, writes dh (f32, global rows)
// MODE 1: retrieve   -> nan0 + pf_rmsnorm + q residual, writes out (merge heads)
template <int MODE>
__global__ __launch_bounds__(256) void k256(
    const u16* __restrict__ A, const float* __restrict__ Bmat, long bstride,
    const u16* __restrict__ keys, const u16* __restrict__ vals,
    const float* __restrict__ theta, const u16* __restrict__ q,
    float* __restrict__ dh, float* __restrict__ outp, long grow0) {
  __shared__ float As[16][68];
  __shared__ float Bs[16][68];
  __shared__ float Cs[64][72];
  int t = threadIdx.x;
  long rowbase = (long)blockIdx.z * S + (long)blockIdx.y * 64;
  const float* Bp = Bmat + (long)blockIdx.z * bstride;
  int am = t >> 2, ak = (t & 3) << 2;
  int bk = t >> 4, bn = (t & 15) << 2;
  int tm = t & 15, tn = t >> 4;
  float acc[4][4] = {};
  for (int k0 = 0; k0 < 256; k0 += 16) {
    ushort4 av = *(const ushort4*)(A + (rowbase + am) * 256 + k0 + ak);
    As[ak + 0][am] = geluf(b2f(av.x));
    As[ak + 1][am] = geluf(b2f(av.y));
    As[ak + 2][am] = geluf(b2f(av.z));
    As[ak + 3][am] = geluf(b2f(av.w));
    *(float4*)&Bs[bk][bn] = *(const float4*)(Bp + (size_t)(k0 + bk) * 64 + bn);
    __syncthreads();
    GEMM_INNER16
    __syncthreads();
  }
#pragma unroll
  for (int ii = 0; ii < 4; ii++)
#pragma unroll
    for (int jj = 0; jj < 4; jj++)
      Cs[tm * 4 + ii][tn * 4 + jj] = acc[ii][jj];
  __syncthreads();
  int row = t >> 2, qd = t & 3;
  long lr = rowbase + row;
  long gr = grow0 + lr;
  float hv[16];
  float ss = 0.f;
#pragma unroll
  for (int j4 = 0; j4 < 4; j4++) {
    float4 v = *(const float4*)&Cs[row][qd * 16 + j4 * 4];
    float a = v.x, b = v.y, c = v.z, d = v.w;
    if (MODE == 1) { a = nan0(a); b = nan0(b); c = nan0(c); d = nan0(d); }
    hv[j4 * 4 + 0] = a; hv[j4 * 4 + 1] = b;
    hv[j4 * 4 + 2] = c; hv[j4 * 4 + 3] = d;
    ss += a * a + b * b + c * c + d * d;
  }
  ss += __shfl_xor(ss, 1, 64);
  ss += __shfl_xor(ss, 2, 64);
  float rms = sqrtf(ss * (1.f / 64) + 1e-8f);
  float rrms = 1.f / rms;
  if (MODE == 0) {
    float th2 = 2.f * theta[gr];
    float hn[16], dp[16];
    float dyp = 0.f;
#pragma unroll
    for (int j4 = 0; j4 < 4; j4++) {
      ushort4 kk4 = *(const ushort4*)&keys[gr * 64 + qd * 16 + j4 * 4];
      ushort4 vv4 = *(const ushort4*)&vals[gr * 64 + qd * 16 + j4 * 4];
      u16 ks[4] = {kk4.x, kk4.y, kk4.z, kk4.w};
      u16 vs[4] = {vv4.x, vv4.y, vv4.z, vv4.w};
#pragma unroll
      for (int j = 0; j < 4; j++) {
        int jj = j4 * 4 + j;
        hn[jj] = hv[jj] * rrms;
        dp[jj] = th2 * (hn[jj] + b2f(ks[j]) - b2f(vs[j]));
        dyp += dp[jj] * hn[jj];
      }
    }
    dyp += __shfl_xor(dyp, 1, 64);
    dyp += __shfl_xor(dyp, 2, 64);
#pragma unroll
    for (int j4 = 0; j4 < 4; j4++) {
      float4 o;
      float* op = (float*)&o;
#pragma unroll
      for (int j = 0; j < 4; j++) {
        int jj = j4 * 4 + j;
        op[j] = (dp[jj] - hn[jj] * dyp * (1.f / 64)) * rrms;
      }
      *(float4*)&dh[gr * 64 + qd * 16 + j4 * 4] = o;
    }
  } else {
    long bh = gr >> 11, s_ = gr & 2047;
    long b = bh >> 4, hh = bh & 15;
    long obase = (b * S + s_) * D + hh * 64 + qd * 16;
#pragma unroll
    for (int j4 = 0; j4 < 4; j4++) {
      ushort4 q4 = *(const ushort4*)&q[gr * 64 + qd * 16 + j4 * 4];
      float4 o;
      o.x = hv[j4 * 4 + 0] * rrms + b2f(q4.x);
      o.y = hv[j4 * 4 + 1] * rrms + b2f(q4.y);
      o.z = hv[j4 * 4 + 2] * rrms + b2f(q4.z);
      o.w = hv[j4 * 4 + 3] * rrms + b2f(q4.w);
      *(float4*)&outp[obase + j4 * 4] = o;
    }
  }
}

// ---------------- transpose W1 (256x64) -> W1t (64x256) ----------------
__global__ void k_trans_w1(const float* __restrict__ W1, float* __restrict__ W1t) {
  int i = blockIdx.x * 256 + threadIdx.x;
  int k = i >> 8, n = i & 255;
  W1t[i] = W1[n * 64 + k];
}

// ---------------- g1[bh](256x64) = gelu(pre0)^T @ dh, K=2048 (local bh) ----------------
__global__ __launch_bounds__(256) void k_g1(const u16* __restrict__ pre0,
                                            const float* __restrict__ dh,
                                            float* __restrict__ g1) {
  __shared__ float As[16][68];
  __shared__ float Bs[16][68];
  int t = threadIdx.x;
  int z = blockIdx.z, i0 = blockIdx.y * 64;
  long base = (long)z * S;
  int sk = t >> 4, sc = (t & 15) << 2;
  int tm = t & 15, tn = t >> 4;
  float acc[4][4] = {};
  for (int s0 = 0; s0 < S; s0 += 16) {
    ushort4 av = *(const ushort4*)(pre0 + (base + s0 + sk) * 256 + i0 + sc);
    As[sk][sc + 0] = geluf(b2f(av.x));
    As[sk][sc + 1] = geluf(b2f(av.y));
    As[sk][sc + 2] = geluf(b2f(av.z));
    As[sk][sc + 3] = geluf(b2f(av.w));
    *(float4*)&Bs[sk][sc] = *(const float4*)(dh + (base + s0 + sk) * 64 + sc);
    __syncthreads();
    GEMM_INNER16
    __syncthreads();
  }
#pragma unroll
  for (int ii = 0; ii < 4; ii++)
#pragma unroll
    for (int jj = 0; jj < 4; jj++)
      g1[(long)z * 16384 + (size_t)(i0 + tm * 4 + ii) * 64 + tn * 4 + jj] = acc[ii][jj];
}

// ---------------- g0[bh](64x256) = keys^T @ dh0, K=2048 (local bh) ----------------
__global__ __launch_bounds__(256) void k_g0(const u16* __restrict__ keys,
                                            const u16* __restrict__ dh0,
                                            float* __restrict__ g0) {
  __shared__ float As[16][68];
  __shared__ float Bs[16][68];
  int t = threadIdx.x;
  int z = blockIdx.z, n0 = blockIdx.x * 64;
  long base = (long)z * S;
  int sk = t >> 4, sc = (t & 15) << 2;
  int tm = t & 15, tn = t >> 4;
  float acc[4][4] = {};
  for (int s0 = 0; s0 < S; s0 += 16) {
    ushort4 av = *(const ushort4*)(keys + (base + s0 + sk) * 64 + sc);
    As[sk][sc + 0] = b2f(av.x); As[sk][sc + 1] = b2f(av.y);
    As[sk][sc + 2] = b2f(av.z); As[sk][sc + 3] = b2f(av.w);
    ushort4 bv = *(const ushort4*)(dh0 + (base + s0 + sk) * 256 + n0 + sc);
    Bs[sk][sc + 0] = b2f(bv.x); Bs[sk][sc + 1] = b2f(bv.y);
    Bs[sk][sc + 2] = b2f(bv.z); Bs[sk][sc + 3] = b2f(bv.w);
    __syncthreads();
    GEMM_INNER16
    __syncthreads();
  }
#pragma unroll
  for (int ii = 0; ii < 4; ii++)
#pragma unroll
    for (int jj = 0; jj < 4; jj++)
      g0[(long)z * 16384 + (size_t)(tm * 4 + ii) * 256 + n0 + tn * 4 + jj] = acc[ii][jj];
}

// ---------------- grad-norm clip coefficient per bh ----------------
__global__ void k_clip(const float* __restrict__ g0, const float* __restrict__ g1,
                       float* __restrict__ coef) {
  int bh = blockIdx.x, t = threadIdx.x;
  const float* p0 = g0 + (long)bh * 16384;
  const float* p1 = g1 + (long)bh * 16384;
  float s = 0.f;
  for (int i = t; i < 16384; i += 256) {
    float a = p0[i]; s += a * a;
    float b = p1[i]; s += b * b;
  }
  s = wsum(s);
  __shared__ float sh[4];
  int w = t >> 6, lane = t & 63;
  if (lane == 0) sh[w] = s;
  __syncthreads();
  if (t == 0) {
    float tot = sh[0] + sh[1] + sh[2] + sh[3];
    float c = 10.f / (sqrtf(tot) + 1e-6f);
    coef[bh] = fminf(c, 1.f);
  }
}

// ---------------- weight update ----------------
__global__ void k_update(const float* __restrict__ W, const float* __restrict__ g,
                         const float* __restrict__ amean, const float* __restrict__ coef,
                         float* __restrict__ nW) {
  long i = (long)blockIdx.x * 256 + threadIdx.x;
  int bh = (int)(i >> 14);
  int idx = (int)(i & 16383);
  float w = W[idx];
  float nw = (1.f - amean[bh]) * w - coef[bh] * g[i];
  if (!finitef(nw)) nw = w;
  nW[i] = nw;
}

extern "C" void kernel_launch(void* const* d_in, const int* in_sizes, int n_in,
                              void* d_out, int out_size, void* d_ws, size_t ws_size,
                              hipStream_t stream) {
  const float* x   = (const float*)d_in[0];
  const float* W_K = (const float*)d_in[1];
  const float* W_V = (const float*)d_in[2];
  const float* W_Q = (const float*)d_in[3];
  const float* mW0 = (const float*)d_in[4];
  const float* mW1 = (const float*)d_in[5];
  const float* knw = (const float*)d_in[6];
  const float* qnw = (const float*)d_in[7];
  const float* snw = (const float*)d_in[8];
  const float* rnw = (const float*)d_in[9];
  const float* aw  = (const float*)d_in[10];
  const float* ab  = (const float*)d_in[11];
  const float* tw  = (const float*)d_in[12];
  const float* tb  = (const float*)d_in[13];
  float* out = (float*)d_out;
  (void)ws_size; (void)in_sizes; (void)n_in; (void)out_size;

  // workspace carve-up (~170 MB); dh (64 MB) lives in d_out until retrieve.
  char* w = (char*)d_ws;
  auto alloc = [&](size_t bytes) {
    char* p = w;
    w += (bytes + 255) / 256 * 256;
    return p;
  };
  float* rinv  = (float*)alloc((size_t)BS * 4);
  u16*   keys  = (u16*)alloc(NR * 64 * 2);          // reused as q in retrieve
  u16*   vals  = (u16*)alloc(NR * 64 * 2);
  float* alpha = (float*)alloc(NR * 4);
  float* theta = (float*)alloc(NR * 4);
  float* amean = (float*)alloc(BH * 4);
  float* coef  = (float*)alloc(BH * 4);
  u16*   pre0g = (u16*)alloc((size_t)GB * S * 256 * 2);  // 32 MB (group)
  u16*   dh0g  = (u16*)alloc((size_t)GB * S * 256 * 2);  // 32 MB (group)
  float* g0    = (float*)alloc((size_t)BH * 16384 * 4);
  float* g1    = (float*)alloc((size_t)BH * 16384 * 4);
  float* nW0   = (float*)alloc((size_t)BH * 16384 * 4);
  float* nW1   = (float*)alloc((size_t)BH * 16384 * 4);
  float* W1t   = (float*)alloc((size_t)16384 * 4);
  float* dh    = (float*)d_out;  // 64 MB scratch, dead before final writes

  // ---- store path ----
  k_rowrms<<<BS / 4, 256, 0, stream>>>(x, rinv);
  k_proj<true><<<dim3(16, 256), 256, 0, stream>>>(x, W_K, rinv, snw, knw, keys);
  k_proj<false><<<dim3(16, 256), 256, 0, stream>>>(x, W_V, rinv, snw, nullptr, vals);
  k_ate<<<BS / 64, 256, 0, stream>>>(x, rinv, snw, aw, ab, tw, tb, alpha, theta);
  k_mean<<<BH, 256, 0, stream>>>(alpha, amean);
  k_trans_w1<<<64, 256, 0, stream>>>(mW1, W1t);

  // ---- memory grad (4 groups of 32 bh to bound workspace) ----
  for (int g = 0; g < NG; g++) {
    long bh0 = (long)g * GB;
    long grow0 = bh0 * S;
    const u16* keys_g = keys + grow0 * 64;
    k64<0><<<dim3(4, GB * S / 64, 1), 256, 0, stream>>>(
        keys_g, nullptr, mW0, 0, nullptr, pre0g);
    k256<0><<<dim3(1, GB * S / 64, 1), 256, 0, stream>>>(
        pre0g, mW1, 0, keys, vals, theta, nullptr, dh, nullptr, grow0);
    k64<1><<<dim3(4, GB * S / 64, 1), 256, 0, stream>>>(
        nullptr, dh + grow0 * 64, W1t, 0, pre0g, dh0g);
    k_g1<<<dim3(1, 4, GB), 256, 0, stream>>>(pre0g, dh + grow0 * 64, g1 + bh0 * 16384);
    k_g0<<<dim3(4, 1, GB), 256, 0, stream>>>(keys_g, dh0g, g0 + bh0 * 16384);
  }
  k_clip<<<BH, 256, 0, stream>>>(g0, g1, coef);
  k_update<<<BH * 16384 / 256, 256, 0, stream>>>(mW0, g0, amean, coef, nW0);
  k_update<<<BH * 16384 / 256, 256, 0, stream>>>(mW1, g1, amean, coef, nW1);

  // ---- retrieve (q overwrites keys buffer; pre0g reused per group) ----
  u16* q = keys;
  k_proj<true><<<dim3(16, 256), 256, 0, stream>>>(x, W_Q, rinv, rnw, qnw, q);
  for (int g = 0; g < NG; g++) {
    long bh0 = (long)g * GB;
    long grow0 = bh0 * S;
    k64<0><<<dim3(4, S / 64, GB), 256, 0, stream>>>(
        q + grow0 * 64, nullptr, nW0 + bh0 * 16384, 16384, nullptr, pre0g);
    k256<1><<<dim3(1, S / 64, GB), 256, 0, stream>>>(
        pre0g, nW1 + bh0 * 16384, 16384, nullptr, nullptr, nullptr, q, nullptr, out, grow0);
  }
}

// Round 3
// 2008.867 us; speedup vs baseline: 1.9026x; 1.9026x over previous
//
#include <hip/hip_runtime.h>

typedef unsigned short u16;
typedef unsigned int   u32;

#define DEV static __device__ __forceinline__

constexpr int S   = 2048;
constexpr int D   = 1024;
constexpr int H   = 16;
constexpr int BB  = 8;
constexpr int BH  = BB * H;        // 128
constexpr int BS  = BB * S;        // 16384 (b,s) rows
constexpr long NR = (long)BH * S;  // 262144 (bh,s) rows
constexpr int GB  = 32;            // bh per group
constexpr int NG  = BH / GB;       // 4 groups
constexpr int NCH = 8;             // split-K chunks for g0/g1
constexpr int SCH = S / NCH;       // 256

typedef __attribute__((ext_vector_type(8))) short bf16x8;
typedef __attribute__((ext_vector_type(4))) float f32x4;

DEV float b2f(u16 u) { return __uint_as_float(((u32)u) << 16); }
DEV u16   f2b(float f) {
  u32 x = __float_as_uint(f);
  u32 r = (x + 0x7fffu + ((x >> 16) & 1u)) >> 16;
  return (u16)r;
}
DEV float geluf(float x) { return 0.5f * x * (1.0f + erff(x * 0.70710678118654752440f)); }
DEV float gelu_gradf(float x) {
  float cdf = 0.5f * (1.0f + erff(x * 0.70710678118654752440f));
  float pdf = expf(-0.5f * x * x) * 0.3989422804014327f;
  return cdf + x * pdf;
}
DEV float sigmoidf(float z) { return 1.0f / (1.0f + expf(-z)); }
DEV float wsum(float v) {
#pragma unroll
  for (int o = 32; o > 0; o >>= 1) v += __shfl_xor(v, o, 64);
  return v;
}
DEV float nan0(float v) {
  u32 b = __float_as_uint(v);
  return ((b & 0x7f800000u) == 0x7f800000u) ? 0.f : v;
}
DEV bool finitef(float v) {
  u32 b = __float_as_uint(v);
  return (b & 0x7f800000u) != 0x7f800000u;
}
DEV void dma16(const void* g, void* l) {
  __builtin_amdgcn_global_load_lds((const __attribute__((address_space(1))) void*)g,
                                   (__attribute__((address_space(3))) void*)l, 16, 0, 0);
}
DEV int swz4(int r) { return (r ^ (r >> 2)) & 3; }

// 16-step k inner product on staged LDS tiles (64x64 tile, 4x4 per thread)
#define GEMM_INNER16                                        \
  _Pragma("unroll")                                         \
  for (int kk = 0; kk < 16; kk++) {                         \
    float4 a4 = *(const float4*)&As[kk][tm << 2];           \
    float4 b4 = *(const float4*)&Bs[kk][tn << 2];           \
    float aa[4] = {a4.x, a4.y, a4.z, a4.w};                 \
    float bb[4] = {b4.x, b4.y, b4.z, b4.w};                 \
    _Pragma("unroll") for (int ii = 0; ii < 4; ii++)        \
      _Pragma("unroll") for (int jj = 0; jj < 4; jj++)      \
        acc[ii][jj] += aa[ii] * bb[jj];                     \
  }

// ---- x-normalize: (optionally compute rinv) and emit bf16 x*rinv*cw ----
template <bool FIRST>
__global__ void k_xnorm(const float* __restrict__ x, const float* __restrict__ cw,
                        float* __restrict__ rinv, u16* __restrict__ xb) {
  int row  = blockIdx.x * 4 + (threadIdx.x >> 6);
  int lane = threadIdx.x & 63;
  const float* p = x + (size_t)row * D;
  float4 v[4];
#pragma unroll
  for (int j = 0; j < 4; j++) v[j] = *(const float4*)(p + lane * 4 + j * 256);
  float rs;
  if (FIRST) {
    float s = 0.f;
#pragma unroll
    for (int j = 0; j < 4; j++)
      s += v[j].x * v[j].x + v[j].y * v[j].y + v[j].z * v[j].z + v[j].w * v[j].w;
    s = wsum(s);
    rs = rsqrtf(s * (1.0f / D) + 1e-6f);
    if (lane == 0) rinv[row] = rs;
  } else {
    rs = rinv[row];
  }
#pragma unroll
  for (int j = 0; j < 4; j++) {
    float4 w4 = *(const float4*)(cw + lane * 4 + j * 256);
    ushort4 o;
    o.x = f2b(v[j].x * rs * w4.x);
    o.y = f2b(v[j].y * rs * w4.y);
    o.z = f2b(v[j].z * rs * w4.z);
    o.w = f2b(v[j].w * rs * w4.w);
    *(ushort4*)&xb[(size_t)row * D + lane * 4 + j * 256] = o;
  }
}

// ---- transpose+convert the three projection weights -> WT[n][k] bf16 ----
__global__ void k_wtrans(const float* __restrict__ W0, const float* __restrict__ W1,
                         const float* __restrict__ W2, u16* __restrict__ WT) {
  __shared__ float tl[64][65];
  const float* W = blockIdx.z == 0 ? W0 : blockIdx.z == 1 ? W1 : W2;
  u16* dst = WT + (size_t)blockIdx.z * D * D;
  int bx = blockIdx.x, by = blockIdx.y;
  int t = threadIdx.x;
  int r = t >> 6, c = t & 63;
#pragma unroll
  for (int i = 0; i < 64; i += 4)
    tl[i + r][c] = W[(size_t)(bx * 64 + i + r) * D + by * 64 + c];
  __syncthreads();
#pragma unroll
  for (int i = 0; i < 64; i += 4)
    dst[(size_t)(by * 64 + i + r) * D + bx * 64 + c] = f2b(tl[c][i + r]);
}

// ---- MFMA projection GEMM: xb(16384x1024 bf16) @ W (via WT[n][k] bf16) ----
// 128x128 tile, BK=32, global_load_lds staging with XOR chunk swizzle.
// Fused head-split (+per-head RMSNorm) epilogue -> bf16 (BH,S,64).
template <bool NORM>
__global__ __launch_bounds__(256) void k_proj_mfma(
    const u16* __restrict__ xb, const u16* __restrict__ WT,
    const float* __restrict__ hw, u16* __restrict__ outp) {
  __shared__ u16 As[128 * 32];
  __shared__ u16 Bs[128 * 32];
  int t = threadIdx.x;
  int wave = t >> 6, lane = t & 63;
  int wm = wave >> 1, wn = wave & 1;
  int m0 = blockIdx.y * 128, n0 = blockIdx.x * 128;
  int quad = lane >> 4, l15 = lane & 15;
  int rl = lane >> 2;
  int q  = (lane & 3) ^ swz4(rl);

  f32x4 acc[4][4] = {};

  int aoff[4], boff[4];
#pragma unroll
  for (int f = 0; f < 4; f++) {
    int ra = wm * 64 + f * 16 + l15;
    aoff[f] = ra * 32 + (quad ^ swz4(l15)) * 8;
    int rb = wn * 64 + f * 16 + l15;
    boff[f] = rb * 32 + (quad ^ swz4(l15)) * 8;
  }
  const u16* ga0 = xb + (size_t)(m0 + wave * 32 + rl) * D + q * 8;
  const u16* ga1 = xb + (size_t)(m0 + wave * 32 + 16 + rl) * D + q * 8;
  const u16* gb0 = WT + (size_t)(n0 + wave * 32 + rl) * D + q * 8;
  const u16* gb1 = WT + (size_t)(n0 + wave * 32 + 16 + rl) * D + q * 8;
  u16* lA0 = &As[(wave * 32) * 32];
  u16* lA1 = &As[(wave * 32 + 16) * 32];
  u16* lB0 = &Bs[(wave * 32) * 32];
  u16* lB1 = &Bs[(wave * 32 + 16) * 32];

  for (int k0 = 0; k0 < D; k0 += 32) {
    dma16(ga0 + k0, lA0);
    dma16(ga1 + k0, lA1);
    dma16(gb0 + k0, lB0);
    dma16(gb1 + k0, lB1);
    __syncthreads();
    bf16x8 af[4], bfr[4];
#pragma unroll
    for (int f = 0; f < 4; f++) {
      af[f]  = *(const bf16x8*)&As[aoff[f]];
      bfr[f] = *(const bf16x8*)&Bs[boff[f]];
    }
#pragma unroll
    for (int i = 0; i < 4; i++)
#pragma unroll
      for (int j = 0; j < 4; j++)
        acc[i][j] = __builtin_amdgcn_mfma_f32_16x16x32_bf16(af[i], bfr[j], acc[i][j], 0, 0, 0);
    __syncthreads();
  }

  // epilogue: wave (wm,wn) owns rows m0+wm*64..+64, head h = bx*2+wn (cols 0..63)
  int h = blockIdx.x * 2 + wn;
  float hwv[4];
  if (NORM) {
#pragma unroll
    for (int f = 0; f < 4; f++) hwv[f] = hw[f * 16 + l15];
  }
#pragma unroll
  for (int fm = 0; fm < 4; fm++) {
    f32x4 rn = {};
    if (NORM) {
      f32x4 ss = acc[fm][0] * acc[fm][0] + acc[fm][1] * acc[fm][1] +
                 acc[fm][2] * acc[fm][2] + acc[fm][3] * acc[fm][3];
#pragma unroll
      for (int c = 0; c < 4; c++) {
        float s = ss[c];
        s += __shfl_xor(s, 1, 64);
        s += __shfl_xor(s, 2, 64);
        s += __shfl_xor(s, 4, 64);
        s += __shfl_xor(s, 8, 64);
        rn[c] = rsqrtf(s * (1.f / 64) + 1e-6f);
      }
    }
#pragma unroll
    for (int r = 0; r < 4; r++) {
      int gr = m0 + wm * 64 + fm * 16 + quad * 4 + r;
      int b = gr >> 11, s_ = gr & 2047;
      size_t base = ((size_t)(b * 16 + h) * S + s_) * 64 + l15;
#pragma unroll
      for (int fn = 0; fn < 4; fn++) {
        float v = acc[fm][fn][r];
        if (NORM) v *= rn[r] * hwv[fn];
        outp[base + fn * 16] = f2b(v);
      }
    }
  }
}

// ---------------- alpha / theta: sigmoid(x_n @ [aw|tw] + bias) ----------------
__global__ __launch_bounds__(256) void k_ate(
    const float* __restrict__ x, const float* __restrict__ rinv, const float* __restrict__ snw,
    const float* __restrict__ aw, const float* __restrict__ ab,
    const float* __restrict__ tw, const float* __restrict__ tb,
    float* __restrict__ alpha, float* __restrict__ theta) {
  __shared__ float As[16][68];
  __shared__ float Ws[16][32];
  int t = threadIdx.x;
  int row0 = blockIdx.x * 64;
  int am = t >> 2, ak = (t & 3) << 2;
  float rsc = rinv[row0 + am];
  int m = t & 63, c0 = (t >> 6) * 8;
  float acc[8] = {};
  for (int k0 = 0; k0 < D; k0 += 16) {
    float4 av = *(const float4*)(x + (size_t)(row0 + am) * D + k0 + ak);
    float4 cw = *(const float4*)(snw + k0 + ak);
    As[ak + 0][am] = av.x * rsc * cw.x;
    As[ak + 1][am] = av.y * rsc * cw.y;
    As[ak + 2][am] = av.z * rsc * cw.z;
    As[ak + 3][am] = av.w * rsc * cw.w;
#pragma unroll
    for (int j = 0; j < 2; j++) {
      int idx = t * 2 + j;
      int kk = idx >> 5, c = idx & 31;
      Ws[kk][c] = (c < 16) ? aw[(size_t)(k0 + kk) * 16 + c]
                           : tw[(size_t)(k0 + kk) * 16 + (c - 16)];
    }
    __syncthreads();
#pragma unroll
    for (int kk = 0; kk < 16; kk++) {
      float a = As[kk][m];
#pragma unroll
      for (int j = 0; j < 8; j++) acc[j] += a * Ws[kk][c0 + j];
    }
    __syncthreads();
  }
  int r = row0 + m;
  int b = r >> 11, s_ = r & 2047;
#pragma unroll
  for (int j = 0; j < 8; j++) {
    int c = c0 + j;
    int g = c >> 4, hh = c & 15;
    float bias = g ? tb[hh] : ab[hh];
    float v = sigmoidf(acc[j] + bias);
    if (g) v *= 0.01f;  // MAX_LR
    float* dst = g ? theta : alpha;
    dst[(long)(b * 16 + hh) * S + s_] = v;
  }
}

// ---------------- per-bh mean of alpha ----------------
__global__ void k_mean(const float* __restrict__ alpha, float* __restrict__ amean) {
  int bh = blockIdx.x, t = threadIdx.x;
  float sa = 0.f;
  for (int i = t; i < S; i += 256) sa += alpha[(long)bh * S + i];
  sa = wsum(sa);
  __shared__ float sh[4];
  int w = t >> 6, lane = t & 63;
  if (lane == 0) sh[w] = sa;
  __syncthreads();
  if (t == 0) amean[bh] = (sh[0] + sh[1] + sh[2] + sh[3]) * (1.f / S);
}

// -------- K=64 GEMM: rows x 64 @ 64x256 -> bf16 (row-stride 256) --------
template <int MODE>
__global__ __launch_bounds__(256) void k64(
    const u16* __restrict__ Ab, const float* __restrict__ Af,
    const float* __restrict__ Bmat, long bstride,
    const u16* __restrict__ aux, u16* __restrict__ out) {
  __shared__ float As[16][68];
  __shared__ float Bs[16][68];
  int t = threadIdx.x;
  int n0 = blockIdx.x * 64;
  long rowbase = (long)blockIdx.z * S + (long)blockIdx.y * 64;
  const float* Bp = Bmat + (long)blockIdx.z * bstride;
  int am = t >> 2, ak = (t & 3) << 2;
  int bk = t >> 4, bn = (t & 15) << 2;
  int tm = t & 15, tn = t >> 4;
  float acc[4][4] = {};
  for (int k0 = 0; k0 < 64; k0 += 16) {
    long ar = rowbase + am;
    if (MODE == 1) {
      float4 av = *(const float4*)(Af + ar * 64 + k0 + ak);
      As[ak + 0][am] = av.x; As[ak + 1][am] = av.y;
      As[ak + 2][am] = av.z; As[ak + 3][am] = av.w;
    } else {
      ushort4 av = *(const ushort4*)(Ab + ar * 64 + k0 + ak);
      As[ak + 0][am] = b2f(av.x); As[ak + 1][am] = b2f(av.y);
      As[ak + 2][am] = b2f(av.z); As[ak + 3][am] = b2f(av.w);
    }
    *(float4*)&Bs[bk][bn] = *(const float4*)(Bp + (size_t)(k0 + bk) * 256 + n0 + bn);
    __syncthreads();
    GEMM_INNER16
    __syncthreads();
  }
#pragma unroll
  for (int ii = 0; ii < 4; ii++) {
    long r = rowbase + tm * 4 + ii;
    int c0 = n0 + tn * 4;
    float v[4] = {acc[ii][0], acc[ii][1], acc[ii][2], acc[ii][3]};
    if (MODE == 1) {
      ushort4 a4 = *(const ushort4*)&aux[r * 256 + c0];
      v[0] *= gelu_gradf(b2f(a4.x)); v[1] *= gelu_gradf(b2f(a4.y));
      v[2] *= gelu_gradf(b2f(a4.z)); v[3] *= gelu_gradf(b2f(a4.w));
    }
    ushort4 o;
    o.x = f2b(v[0]); o.y = f2b(v[1]); o.z = f2b(v[2]); o.w = f2b(v[3]);
    *(ushort4*)&out[r * 256 + c0] = o;
  }
}

// -------- K=256 GEMM: rows x 256 (gelu on A) @ 256x64, fused epilogue --------
template <int MODE>
__global__ __launch_bounds__(256) void k256(
    const u16* __restrict__ A, const float* __restrict__ Bmat, long bstride,
    const u16* __restrict__ keys, const u16* __restrict__ vals,
    const float* __restrict__ theta, const u16* __restrict__ q,
    float* __restrict__ dh, float* __restrict__ outp, long grow0) {
  __shared__ float As[16][68];
  __shared__ float Bs[16][68];
  __shared__ float Cs[64][72];
  int t = threadIdx.x;
  long rowbase = (long)blockIdx.z * S + (long)blockIdx.y * 64;
  const float* Bp = Bmat + (long)blockIdx.z * bstride;
  int am = t >> 2, ak = (t & 3) << 2;
  int bk = t >> 4, bn = (t & 15) << 2;
  int tm = t & 15, tn = t >> 4;
  float acc[4][4] = {};
  for (int k0 = 0; k0 < 256; k0 += 16) {
    ushort4 av = *(const ushort4*)(A + (rowbase + am) * 256 + k0 + ak);
    As[ak + 0][am] = geluf(b2f(av.x));
    As[ak + 1][am] = geluf(b2f(av.y));
    As[ak + 2][am] = geluf(b2f(av.z));
    As[ak + 3][am] = geluf(b2f(av.w));
    *(float4*)&Bs[bk][bn] = *(const float4*)(Bp + (size_t)(k0 + bk) * 64 + bn);
    __syncthreads();
    GEMM_INNER16
    __syncthreads();
  }
#pragma unroll
  for (int ii = 0; ii < 4; ii++)
#pragma unroll
    for (int jj = 0; jj < 4; jj++)
      Cs[tm * 4 + ii][tn * 4 + jj] = acc[ii][jj];
  __syncthreads();
  int row = t >> 2, qd = t & 3;
  long lr = rowbase + row;
  long gr = grow0 + lr;
  float hv[16];
  float ss = 0.f;
#pragma unroll
  for (int j4 = 0; j4 < 4; j4++) {
    float4 v = *(const float4*)&Cs[row][qd * 16 + j4 * 4];
    float a = v.x, b = v.y, c = v.z, d = v.w;
    if (MODE == 1) { a = nan0(a); b = nan0(b); c = nan0(c); d = nan0(d); }
    hv[j4 * 4 + 0] = a; hv[j4 * 4 + 1] = b;
    hv[j4 * 4 + 2] = c; hv[j4 * 4 + 3] = d;
    ss += a * a + b * b + c * c + d * d;
  }
  ss += __shfl_xor(ss, 1, 64);
  ss += __shfl_xor(ss, 2, 64);
  float rms = sqrtf(ss * (1.f / 64) + 1e-8f);
  float rrms = 1.f / rms;
  if (MODE == 0) {
    float th2 = 2.f * theta[gr];
    float hn[16], dp[16];
    float dyp = 0.f;
#pragma unroll
    for (int j4 = 0; j4 < 4; j4++) {
      ushort4 kk4 = *(const ushort4*)&keys[gr * 64 + qd * 16 + j4 * 4];
      ushort4 vv4 = *(const ushort4*)&vals[gr * 64 + qd * 16 + j4 * 4];
      u16 ks[4] = {kk4.x, kk4.y, kk4.z, kk4.w};
      u16 vs[4] = {vv4.x, vv4.y, vv4.z, vv4.w};
#pragma unroll
      for (int j = 0; j < 4; j++) {
        int jj = j4 * 4 + j;
        hn[jj] = hv[jj] * rrms;
        dp[jj] = th2 * (hn[jj] + b2f(ks[j]) - b2f(vs[j]));
        dyp += dp[jj] * hn[jj];
      }
    }
    dyp += __shfl_xor(dyp, 1, 64);
    dyp += __shfl_xor(dyp, 2, 64);
#pragma unroll
    for (int j4 = 0; j4 < 4; j4++) {
      float4 o;
      float* op = (float*)&o;
#pragma unroll
      for (int j = 0; j < 4; j++) {
        int jj = j4 * 4 + j;
        op[j] = (dp[jj] - hn[jj] * dyp * (1.f / 64)) * rrms;
      }
      *(float4*)&dh[gr * 64 + qd * 16 + j4 * 4] = o;
    }
  } else {
    long bh = gr >> 11, s_ = gr & 2047;
    long b = bh >> 4, hh = bh & 15;
    long obase = (b * S + s_) * D + hh * 64 + qd * 16;
#pragma unroll
    for (int j4 = 0; j4 < 4; j4++) {
      ushort4 q4 = *(const ushort4*)&q[gr * 64 + qd * 16 + j4 * 4];
      float4 o;
      o.x = hv[j4 * 4 + 0] * rrms + b2f(q4.x);
      o.y = hv[j4 * 4 + 1] * rrms + b2f(q4.y);
      o.z = hv[j4 * 4 + 2] * rrms + b2f(q4.z);
      o.w = hv[j4 * 4 + 3] * rrms + b2f(q4.w);
      *(float4*)&outp[obase + j4 * 4] = o;
    }
  }
}

// ---------------- transpose W1 (256x64) -> W1t (64x256) ----------------
__global__ void k_trans_w1(const float* __restrict__ W1, float* __restrict__ W1t) {
  int i = blockIdx.x * 256 + threadIdx.x;
  int k = i >> 8, n = i & 255;
  W1t[i] = W1[n * 64 + k];
}

// ---------------- zero-fill ----------------
__global__ void k_zero(float* __restrict__ p, long n) {
  long i = (long)blockIdx.x * 256 + threadIdx.x;
  if (i < n) p[i] = 0.f;
}

// ---- g1[z](256x64) += gelu(pre0)^T @ dh over S-chunk (split-K, atomic) ----
__global__ __launch_bounds__(256) void k_g1s(const u16* __restrict__ pre0,
                                             const float* __restrict__ dh,
                                             float* __restrict__ g1) {
  __shared__ float As[16][68];
  __shared__ float Bs[16][68];
  int t = threadIdx.x;
  int z = blockIdx.z, i0 = blockIdx.y * 64, ch = blockIdx.x;
  long base = (long)z * S + (long)ch * SCH;
  int sk = t >> 4, sc = (t & 15) << 2;
  int tm = t & 15, tn = t >> 4;
  float acc[4][4] = {};
  for (int s0 = 0; s0 < SCH; s0 += 16) {
    ushort4 av = *(const ushort4*)(pre0 + (base + s0 + sk) * 256 + i0 + sc);
    As[sk][sc + 0] = geluf(b2f(av.x));
    As[sk][sc + 1] = geluf(b2f(av.y));
    As[sk][sc + 2] = geluf(b2f(av.z));
    As[sk][sc + 3] = geluf(b2f(av.w));
    *(float4*)&Bs[sk][sc] = *(const float4*)(dh + (base + s0 + sk) * 64 + sc);
    __syncthreads();
    GEMM_INNER16
    __syncthreads();
  }
#pragma unroll
  for (int ii = 0; ii < 4; ii++)
#pragma unroll
    for (int jj = 0; jj < 4; jj++)
      atomicAdd(&g1[(long)z * 16384 + (size_t)(i0 + tm * 4 + ii) * 64 + tn * 4 + jj],
                acc[ii][jj]);
}

// ---- g0[z](64x256) += keys^T @ dh0 over S-chunk (split-K, atomic) ----
__global__ __launch_bounds__(256) void k_g0s(const u16* __restrict__ keys,
                                             const u16* __restrict__ dh0,
                                             float* __restrict__ g0) {
  __shared__ float As[16][68];
  __shared__ float Bs[16][68];
  int t = threadIdx.x;
  int z = blockIdx.z, n0 = blockIdx.y * 64, ch = blockIdx.x;
  long base = (long)z * S + (long)ch * SCH;
  int sk = t >> 4, sc = (t & 15) << 2;
  int tm = t & 15, tn = t >> 4;
  float acc[4][4] = {};
  for (int s0 = 0; s0 < SCH; s0 += 16) {
    ushort4 av = *(const ushort4*)(keys + (base + s0 + sk) * 64 + sc);
    As[sk][sc + 0] = b2f(av.x); As[sk][sc + 1] = b2f(av.y);
    As[sk][sc + 2] = b2f(av.z); As[sk][sc + 3] = b2f(av.w);
    ushort4 bv = *(const ushort4*)(dh0 + (base + s0 + sk) * 256 + n0 + sc);
    Bs[sk][sc + 0] = b2f(bv.x); Bs[sk][sc + 1] = b2f(bv.y);
    Bs[sk][sc + 2] = b2f(bv.z); Bs[sk][sc + 3] = b2f(bv.w);
    __syncthreads();
    GEMM_INNER16
    __syncthreads();
  }
#pragma unroll
  for (int ii = 0; ii < 4; ii++)
#pragma unroll
    for (int jj = 0; jj < 4; jj++)
      atomicAdd(&g0[(long)z * 16384 + (size_t)(tm * 4 + ii) * 256 + n0 + tn * 4 + jj],
                acc[ii][jj]);
}

// ---------------- grad-norm clip coefficient per bh ----------------
__global__ void k_clip(const float* __restrict__ g0, const float* __restrict__ g1,
                       float* __restrict__ coef) {
  int bh = blockIdx.x, t = threadIdx.x;
  const float* p0 = g0 + (long)bh * 16384;
  const float* p1 = g1 + (long)bh * 16384;
  float s = 0.f;
  for (int i = t; i < 16384; i += 256) {
    float a = p0[i]; s += a * a;
    float b = p1[i]; s += b * b;
  }
  s = wsum(s);
  __shared__ float sh[4];
  int w = t >> 6, lane = t & 63;
  if (lane == 0) sh[w] = s;
  __syncthreads();
  if (t == 0) {
    float tot = sh[0] + sh[1] + sh[2] + sh[3];
    float c = 10.f / (sqrtf(tot) + 1e-6f);
    coef[bh] = fminf(c, 1.f);
  }
}

// ---------------- weight update ----------------
__global__ void k_update(const float* __restrict__ W, const float* __restrict__ g,
                         const float* __restrict__ amean, const float* __restrict__ coef,
                         float* __restrict__ nW) {
  long i = (long)blockIdx.x * 256 + threadIdx.x;
  int bh = (int)(i >> 14);
  int idx = (int)(i & 16383);
  float w = W[idx];
  float nw = (1.f - amean[bh]) * w - coef[bh] * g[i];
  if (!finitef(nw)) nw = w;
  nW[i] = nw;
}

extern "C" void kernel_launch(void* const* d_in, const int* in_sizes, int n_in,
                              void* d_out, int out_size, void* d_ws, size_t ws_size,
                              hipStream_t stream) {
  const float* x   = (const float*)d_in[0];
  const float* W_K = (const float*)d_in[1];
  const float* W_V = (const float*)d_in[2];
  const float* W_Q = (const float*)d_in[3];
  const float* mW0 = (const float*)d_in[4];
  const float* mW1 = (const float*)d_in[5];
  const float* knw = (const float*)d_in[6];
  const float* qnw = (const float*)d_in[7];
  const float* snw = (const float*)d_in[8];
  const float* rnw = (const float*)d_in[9];
  const float* aw  = (const float*)d_in[10];
  const float* ab  = (const float*)d_in[11];
  const float* tw  = (const float*)d_in[12];
  const float* tb  = (const float*)d_in[13];
  float* out = (float*)d_out;
  (void)ws_size; (void)in_sizes; (void)n_in; (void)out_size;

  // workspace carve-up (~200 MB); dh (64 MB) lives in d_out until retrieve.
  char* w = (char*)d_ws;
  auto alloc = [&](size_t bytes) {
    char* p = w;
    w += (bytes + 255) / 256 * 256;
    return p;
  };
  float* rinv  = (float*)alloc((size_t)BS * 4);
  u16*   xs    = (u16*)alloc((size_t)BS * D * 2);        // 32 MB (xs, later xr)
  u16*   WTb   = (u16*)alloc((size_t)3 * D * D * 2);     // 6 MB
  u16*   keys  = (u16*)alloc(NR * 64 * 2);               // reused as q in retrieve
  u16*   vals  = (u16*)alloc(NR * 64 * 2);
  float* alpha = (float*)alloc(NR * 4);
  float* theta = (float*)alloc(NR * 4);
  float* amean = (float*)alloc(BH * 4);
  float* coef  = (float*)alloc(BH * 4);
  u16*   pre0g = (u16*)alloc((size_t)GB * S * 256 * 2);  // 32 MB (group)
  u16*   dh0g  = (u16*)alloc((size_t)GB * S * 256 * 2);  // 32 MB (group)
  float* g0    = (float*)alloc((size_t)BH * 16384 * 4);  // 8 MB (g1 adjacent)
  float* g1    = (float*)alloc((size_t)BH * 16384 * 4);
  float* nW0   = (float*)alloc((size_t)BH * 16384 * 4);
  float* nW1   = (float*)alloc((size_t)BH * 16384 * 4);
  float* W1t   = (float*)alloc((size_t)16384 * 4);
  float* dh    = (float*)d_out;  // 64 MB scratch, dead before final writes

  // ---- store path ----
  k_xnorm<true><<<BS / 4, 256, 0, stream>>>(x, snw, rinv, xs);
  k_wtrans<<<dim3(16, 16, 3), 256, 0, stream>>>(W_K, W_V, W_Q, WTb);
  k_proj_mfma<true><<<dim3(8, 128), 256, 0, stream>>>(xs, WTb, knw, keys);
  k_proj_mfma<false><<<dim3(8, 128), 256, 0, stream>>>(xs, WTb + (size_t)D * D, nullptr, vals);
  k_ate<<<BS / 64, 256, 0, stream>>>(x, rinv, snw, aw, ab, tw, tb, alpha, theta);
  k_mean<<<BH, 256, 0, stream>>>(alpha, amean);
  k_trans_w1<<<64, 256, 0, stream>>>(mW1, W1t);
  k_zero<<<(int)((2L * BH * 16384 + 255) / 256), 256, 0, stream>>>(g0, 2L * BH * 16384);

  // ---- memory grad (4 groups of 32 bh to bound workspace) ----
  for (int g = 0; g < NG; g++) {
    long bh0 = (long)g * GB;
    long grow0 = bh0 * S;
    const u16* keys_g = keys + grow0 * 64;
    k64<0><<<dim3(4, GB * S / 64, 1), 256, 0, stream>>>(
        keys_g, nullptr, mW0, 0, nullptr, pre0g);
    k256<0><<<dim3(1, GB * S / 64, 1), 256, 0, stream>>>(
        pre0g, mW1, 0, keys, vals, theta, nullptr, dh, nullptr, grow0);
    k64<1><<<dim3(4, GB * S / 64, 1), 256, 0, stream>>>(
        nullptr, dh + grow0 * 64, W1t, 0, pre0g, dh0g);
    k_g1s<<<dim3(NCH, 4, GB), 256, 0, stream>>>(pre0g, dh + grow0 * 64, g1 + bh0 * 16384);
    k_g0s<<<dim3(NCH, 4, GB), 256, 0, stream>>>(keys_g, dh0g, g0 + bh0 * 16384);
  }
  k_clip<<<BH, 256, 0, stream>>>(g0, g1, coef);
  k_update<<<BH * 16384 / 256, 256, 0, stream>>>(mW0, g0, amean, coef, nW0);
  k_update<<<BH * 16384 / 256, 256, 0, stream>>>(mW1, g1, amean, coef, nW1);

  // ---- retrieve (xr overwrites xs; q overwrites keys) ----
  k_xnorm<false><<<BS / 4, 256, 0, stream>>>(x, rnw, rinv, xs);
  u16* q = keys;
  k_proj_mfma<true><<<dim3(8, 128), 256, 0, stream>>>(xs, WTb + (size_t)2 * D * D, qnw, q);
  for (int g = 0; g < NG; g++) {
    long bh0 = (long)g * GB;
    long grow0 = bh0 * S;
    k64<0><<<dim3(4, S / 64, GB), 256, 0, stream>>>(
        q + grow0 * 64, nullptr, nW0 + bh0 * 16384, 16384, nullptr, pre0g);
    k256<1><<<dim3(1, S / 64, GB), 256, 0, stream>>>(
        pre0g, nW1 + bh0 * 16384, 16384, nullptr, nullptr, nullptr, q, nullptr, out, grow0);
  }
}

// Round 4
// 1383.391 us; speedup vs baseline: 2.7628x; 1.4521x over previous
//
#include <hip/hip_runtime.h>

typedef unsigned short u16;
typedef unsigned int   u32;

#define DEV static __device__ __forceinline__

constexpr int S    = 2048;
constexpr int D    = 1024;
constexpr int H    = 16;
constexpr int BB   = 8;
constexpr int BH   = BB * H;        // 128
constexpr int BS   = BB * S;        // 16384 (b,s) rows
constexpr long NR  = (long)BH * S;  // 262144 (bh,s) rows
constexpr int GB   = 16;            // bh per group
constexpr int NG   = BH / GB;       // 8 groups
constexpr int GR   = GB * S;        // rows per group = 32768
constexpr int NSPL = 16;            // split-K chunks for g kernels
constexpr int SCH  = S / NSPL;      // 128

typedef __attribute__((ext_vector_type(8))) short bf16x8;
typedef __attribute__((ext_vector_type(4))) float f32x4;

DEV float b2f(u16 u) { return __uint_as_float(((u32)u) << 16); }
DEV u16   f2b(float f) {
  u32 x = __float_as_uint(f);
  u32 r = (x + 0x7fffu + ((x >> 16) & 1u)) >> 16;
  return (u16)r;
}
DEV float geluf(float x) { return 0.5f * x * (1.0f + erff(x * 0.70710678118654752440f)); }
DEV float gelu_gradf(float x) {
  float cdf = 0.5f * (1.0f + erff(x * 0.70710678118654752440f));
  float pdf = expf(-0.5f * x * x) * 0.3989422804014327f;
  return cdf + x * pdf;
}
DEV float sigmoidf(float z) { return 1.0f / (1.0f + expf(-z)); }
DEV float wsum(float v) {
#pragma unroll
  for (int o = 32; o > 0; o >>= 1) v += __shfl_xor(v, o, 64);
  return v;
}
DEV float rsum16(float v) {
  v += __shfl_xor(v, 1, 64);
  v += __shfl_xor(v, 2, 64);
  v += __shfl_xor(v, 4, 64);
  v += __shfl_xor(v, 8, 64);
  return v;
}
DEV float nan0(float v) {
  u32 b = __float_as_uint(v);
  return ((b & 0x7f800000u) == 0x7f800000u) ? 0.f : v;
}
DEV bool finitef(float v) {
  u32 b = __float_as_uint(v);
  return (b & 0x7f800000u) != 0x7f800000u;
}
DEV void dma16(const void* g, void* l) {
  __builtin_amdgcn_global_load_lds((const __attribute__((address_space(1))) void*)g,
                                   (__attribute__((address_space(3))) void*)l, 16, 0, 0);
}
DEV int swz4(int r) { return (r ^ (r >> 2)) & 3; }

// ---- x-normalize: (optionally compute rinv) and emit bf16 x*rinv*cw ----
template <bool FIRST>
__global__ void k_xnorm(const float* __restrict__ x, const float* __restrict__ cw,
                        float* __restrict__ rinv, u16* __restrict__ xb) {
  int row  = blockIdx.x * 4 + (threadIdx.x >> 6);
  int lane = threadIdx.x & 63;
  const float* p = x + (size_t)row * D;
  float4 v[4];
#pragma unroll
  for (int j = 0; j < 4; j++) v[j] = *(const float4*)(p + lane * 4 + j * 256);
  float rs;
  if (FIRST) {
    float s = 0.f;
#pragma unroll
    for (int j = 0; j < 4; j++)
      s += v[j].x * v[j].x + v[j].y * v[j].y + v[j].z * v[j].z + v[j].w * v[j].w;
    s = wsum(s);
    rs = rsqrtf(s * (1.0f / D) + 1e-6f);
    if (lane == 0) rinv[row] = rs;
  } else {
    rs = rinv[row];
  }
#pragma unroll
  for (int j = 0; j < 4; j++) {
    float4 w4 = *(const float4*)(cw + lane * 4 + j * 256);
    ushort4 o;
    o.x = f2b(v[j].x * rs * w4.x);
    o.y = f2b(v[j].y * rs * w4.y);
    o.z = f2b(v[j].z * rs * w4.z);
    o.w = f2b(v[j].w * rs * w4.w);
    *(ushort4*)&xb[(size_t)row * D + lane * 4 + j * 256] = o;
  }
}

// ---- transpose+convert the three projection weights -> WT[n][k] bf16 ----
__global__ void k_wtrans(const float* __restrict__ W0, const float* __restrict__ W1,
                         const float* __restrict__ W2, u16* __restrict__ WT) {
  __shared__ float tl[64][65];
  const float* W = blockIdx.z == 0 ? W0 : blockIdx.z == 1 ? W1 : W2;
  u16* dst = WT + (size_t)blockIdx.z * D * D;
  int bx = blockIdx.x, by = blockIdx.y;
  int t = threadIdx.x;
  int r = t >> 6, c = t & 63;
#pragma unroll
  for (int i = 0; i < 64; i += 4)
    tl[i + r][c] = W[(size_t)(bx * 64 + i + r) * D + by * 64 + c];
  __syncthreads();
#pragma unroll
  for (int i = 0; i < 64; i += 4)
    dst[(size_t)(by * 64 + i + r) * D + bx * 64 + c] = f2b(tl[c][i + r]);
}

// ---- MFMA projection GEMM: xb(16384x1024 bf16) @ W (via WT[n][k] bf16) ----
template <bool NORM>
__global__ __launch_bounds__(256) void k_proj_mfma(
    const u16* __restrict__ xb, const u16* __restrict__ WT,
    const float* __restrict__ hw, u16* __restrict__ outp) {
  __shared__ u16 As[128 * 32];
  __shared__ u16 Bs[128 * 32];
  int t = threadIdx.x;
  int wave = t >> 6, lane = t & 63;
  int wm = wave >> 1, wn = wave & 1;
  int m0 = blockIdx.y * 128, n0 = blockIdx.x * 128;
  int quad = lane >> 4, l15 = lane & 15;
  int rl = lane >> 2;
  int q  = (lane & 3) ^ swz4(rl);

  f32x4 acc[4][4] = {};

  int aoff[4], boff[4];
#pragma unroll
  for (int f = 0; f < 4; f++) {
    aoff[f] = (wm * 64 + f * 16 + l15) * 32 + (quad ^ swz4(l15)) * 8;
    boff[f] = (wn * 64 + f * 16 + l15) * 32 + (quad ^ swz4(l15)) * 8;
  }
  const u16* ga0 = xb + (size_t)(m0 + wave * 32 + rl) * D + q * 8;
  const u16* ga1 = ga0 + 16 * D;
  const u16* gb0 = WT + (size_t)(n0 + wave * 32 + rl) * D + q * 8;
  const u16* gb1 = gb0 + 16 * D;
  u16* lA0 = &As[(wave * 32) * 32];
  u16* lA1 = &As[(wave * 32 + 16) * 32];
  u16* lB0 = &Bs[(wave * 32) * 32];
  u16* lB1 = &Bs[(wave * 32 + 16) * 32];

  for (int k0 = 0; k0 < D; k0 += 32) {
    dma16(ga0 + k0, lA0);
    dma16(ga1 + k0, lA1);
    dma16(gb0 + k0, lB0);
    dma16(gb1 + k0, lB1);
    __syncthreads();
    bf16x8 af[4], bfr[4];
#pragma unroll
    for (int f = 0; f < 4; f++) {
      af[f]  = *(const bf16x8*)&As[aoff[f]];
      bfr[f] = *(const bf16x8*)&Bs[boff[f]];
    }
#pragma unroll
    for (int i = 0; i < 4; i++)
#pragma unroll
      for (int j = 0; j < 4; j++)
        acc[i][j] = __builtin_amdgcn_mfma_f32_16x16x32_bf16(af[i], bfr[j], acc[i][j], 0, 0, 0);
    __syncthreads();
  }

  int h = blockIdx.x * 2 + wn;
  float hwv[4];
  if (NORM) {
#pragma unroll
    for (int f = 0; f < 4; f++) hwv[f] = hw[f * 16 + l15];
  }
#pragma unroll
  for (int fm = 0; fm < 4; fm++) {
    f32x4 rn = {};
    if (NORM) {
      f32x4 ss = acc[fm][0] * acc[fm][0] + acc[fm][1] * acc[fm][1] +
                 acc[fm][2] * acc[fm][2] + acc[fm][3] * acc[fm][3];
#pragma unroll
      for (int c = 0; c < 4; c++) {
        float s = rsum16(ss[c]);
        rn[c] = rsqrtf(s * (1.f / 64) + 1e-6f);
      }
    }
#pragma unroll
    for (int r = 0; r < 4; r++) {
      int gr = m0 + wm * 64 + fm * 16 + quad * 4 + r;
      int b = gr >> 11, s_ = gr & 2047;
      size_t base = ((size_t)(b * 16 + h) * S + s_) * 64 + l15;
#pragma unroll
      for (int fn = 0; fn < 4; fn++) {
        float v = acc[fm][fn][r];
        if (NORM) v *= rn[r] * hwv[fn];
        outp[base + fn * 16] = f2b(v);
      }
    }
  }
}

// ---------------- alpha / theta: sigmoid(x_n @ [aw|tw] + bias) ----------------
__global__ __launch_bounds__(256) void k_ate(
    const float* __restrict__ x, const float* __restrict__ rinv, const float* __restrict__ snw,
    const float* __restrict__ aw, const float* __restrict__ ab,
    const float* __restrict__ tw, const float* __restrict__ tb,
    float* __restrict__ alpha, float* __restrict__ theta) {
  __shared__ float As[16][68];
  __shared__ float Ws[16][32];
  int t = threadIdx.x;
  int row0 = blockIdx.x * 64;
  int am = t >> 2, ak = (t & 3) << 2;
  float rsc = rinv[row0 + am];
  int m = t & 63, c0 = (t >> 6) * 8;
  float acc[8] = {};
  for (int k0 = 0; k0 < D; k0 += 16) {
    float4 av = *(const float4*)(x + (size_t)(row0 + am) * D + k0 + ak);
    float4 cw = *(const float4*)(snw + k0 + ak);
    As[ak + 0][am] = av.x * rsc * cw.x;
    As[ak + 1][am] = av.y * rsc * cw.y;
    As[ak + 2][am] = av.z * rsc * cw.z;
    As[ak + 3][am] = av.w * rsc * cw.w;
#pragma unroll
    for (int j = 0; j < 2; j++) {
      int idx = t * 2 + j;
      int kk = idx >> 5, c = idx & 31;
      Ws[kk][c] = (c < 16) ? aw[(size_t)(k0 + kk) * 16 + c]
                           : tw[(size_t)(k0 + kk) * 16 + (c - 16)];
    }
    __syncthreads();
#pragma unroll
    for (int kk = 0; kk < 16; kk++) {
      float a = As[kk][m];
#pragma unroll
      for (int j = 0; j < 8; j++) acc[j] += a * Ws[kk][c0 + j];
    }
    __syncthreads();
  }
  int r = row0 + m;
  int b = r >> 11, s_ = r & 2047;
#pragma unroll
  for (int j = 0; j < 8; j++) {
    int c = c0 + j;
    int g = c >> 4, hh = c & 15;
    float bias = g ? tb[hh] : ab[hh];
    float v = sigmoidf(acc[j] + bias);
    if (g) v *= 0.01f;  // MAX_LR
    float* dst = g ? theta : alpha;
    dst[(long)(b * 16 + hh) * S + s_] = v;
  }
}

// ---------------- per-bh mean of alpha ----------------
__global__ void k_mean(const float* __restrict__ alpha, float* __restrict__ amean) {
  int bh = blockIdx.x, t = threadIdx.x;
  float sa = 0.f;
  for (int i = t; i < S; i += 256) sa += alpha[(long)bh * S + i];
  sa = wsum(sa);
  __shared__ float sh[4];
  int w = t >> 6, lane = t & 63;
  if (lane == 0) sh[w] = sa;
  __syncthreads();
  if (t == 0) amean[bh] = (sh[0] + sh[1] + sh[2] + sh[3]) * (1.f / S);
}

// ---- small-weight prep: W0T[i][k], W1b[i][o] (direct), W1T[o][i] bf16 ----
__global__ void k_wsmall(const float* __restrict__ W0, const float* __restrict__ W1,
                         u16* __restrict__ W0T, u16* __restrict__ W1b, u16* __restrict__ W1T) {
  int idx = blockIdx.x * 256 + threadIdx.x;  // 16384
  int sec = blockIdx.y;
  if (sec == 0) {
    int k = idx & 63, i = idx >> 6;
    W0T[idx] = f2b(W0[k * 256 + i]);
  } else if (sec == 1) {
    W1b[idx] = f2b(W1[idx]);
  } else {
    int i = idx & 255, o = idx >> 8;
    W1T[idx] = f2b(W1[i * 64 + o]);
  }
}

// ---- keys (group rows, row-major [s][64]) -> blocked-T tiles [s16*4+c16][(col%16)*16+s%16] ----
__global__ void k_keysT(const u16* __restrict__ keysg, u16* __restrict__ blk) {
  int idx = blockIdx.x * 256 + threadIdx.x;  // GR/4 * 64
  int col = idx & 63;
  int s = (idx >> 6) * 4;
  ushort4 o;
  o.x = keysg[(size_t)s * 64 + col];
  o.y = keysg[(size_t)(s + 1) * 64 + col];
  o.z = keysg[(size_t)(s + 2) * 64 + col];
  o.w = keysg[(size_t)(s + 3) * 64 + col];
  *(ushort4*)&blk[((size_t)(s >> 4) * 4 + (col >> 4)) * 256 + (col & 15) * 16 + (s & 15)] = o;
}

// -------- MFMA K=64 GEMM: A[rows][64] @ BT[n=256][k=64] --------
// MODE 0: A=keys  -> act0=gelu, gp=gelu', act0T blocked
// MODE 1: A=dhg   -> dh0 = v*gp, blocked dh0T only
// MODE 2: A=q     -> act0=gelu(h1) only   (per-bh B via bstride, blockIdx.z)
template <int MODE>
__global__ __launch_bounds__(256) void km64(
    const u16* __restrict__ A, const u16* __restrict__ BT, long bstride,
    const u16* __restrict__ gp, u16* __restrict__ o_act, u16* __restrict__ o_gp,
    u16* __restrict__ o_blk) {
  __shared__ u16 As[128 * 32];
  __shared__ u16 Bs[128 * 32];
  int t = threadIdx.x;
  int wave = t >> 6, lane = t & 63;
  int wm = wave >> 1, wn = wave & 1;
  long rowbase = (long)blockIdx.z * S + (long)blockIdx.y * 128;
  int n0 = blockIdx.x * 128;
  int quad = lane >> 4, l15 = lane & 15;
  int rl = lane >> 2;
  int q = (lane & 3) ^ swz4(rl);
  const u16* Bp = BT + (long)blockIdx.z * bstride;

  f32x4 acc[4][4] = {};
  int aoff[4], boff[4];
#pragma unroll
  for (int f = 0; f < 4; f++) {
    aoff[f] = (wm * 64 + f * 16 + l15) * 32 + (quad ^ swz4(l15)) * 8;
    boff[f] = (wn * 64 + f * 16 + l15) * 32 + (quad ^ swz4(l15)) * 8;
  }
  const u16* ga0 = A + (rowbase + wave * 32 + rl) * 64 + q * 8;
  const u16* ga1 = ga0 + 16 * 64;
  const u16* gb0 = Bp + (size_t)(n0 + wave * 32 + rl) * 64 + q * 8;
  const u16* gb1 = gb0 + 16 * 64;
  u16* lA0 = &As[(wave * 32) * 32];
  u16* lA1 = &As[(wave * 32 + 16) * 32];
  u16* lB0 = &Bs[(wave * 32) * 32];
  u16* lB1 = &Bs[(wave * 32 + 16) * 32];

  for (int k0 = 0; k0 < 64; k0 += 32) {
    dma16(ga0 + k0, lA0);
    dma16(ga1 + k0, lA1);
    dma16(gb0 + k0, lB0);
    dma16(gb1 + k0, lB1);
    __syncthreads();
    bf16x8 af[4], bfr[4];
#pragma unroll
    for (int f = 0; f < 4; f++) {
      af[f]  = *(const bf16x8*)&As[aoff[f]];
      bfr[f] = *(const bf16x8*)&Bs[boff[f]];
    }
#pragma unroll
    for (int i = 0; i < 4; i++)
#pragma unroll
      for (int j = 0; j < 4; j++)
        acc[i][j] = __builtin_amdgcn_mfma_f32_16x16x32_bf16(af[i], bfr[j], acc[i][j], 0, 0, 0);
    __syncthreads();
  }

#pragma unroll
  for (int fm = 0; fm < 4; fm++) {
    long sbase = rowbase + wm * 64 + fm * 16;  // group-local, 16-aligned
    long s16 = sbase >> 4;
#pragma unroll
    for (int fn = 0; fn < 4; fn++) {
      int col = n0 + wn * 64 + fn * 16 + l15;
      long c16 = col >> 4;
      size_t tbase = (s16 * 16 + c16) * 256 + l15 * 16 + quad * 4;
      if (MODE == 0) {
        ushort4 ob;
#pragma unroll
        for (int r = 0; r < 4; r++) {
          float v = acc[fm][fn][r];
          float cdf = 0.5f * (1.0f + erff(v * 0.70710678118654752440f));
          float pdf = expf(-0.5f * v * v) * 0.3989422804014327f;
          float a = v * cdf;
          float gd = cdf + v * pdf;
          long row = sbase + quad * 4 + r;
          o_act[row * 256 + col] = f2b(a);
          o_gp[row * 256 + col]  = f2b(gd);
          ((u16*)&ob)[r] = f2b(a);
        }
        *(ushort4*)&o_blk[tbase] = ob;
      } else if (MODE == 1) {
        ushort4 ob;
#pragma unroll
        for (int r = 0; r < 4; r++) {
          long row = sbase + quad * 4 + r;
          float v = acc[fm][fn][r] * b2f(gp[row * 256 + col]);
          ((u16*)&ob)[r] = f2b(v);
        }
        *(ushort4*)&o_blk[tbase] = ob;
      } else {
#pragma unroll
        for (int r = 0; r < 4; r++) {
          long row = sbase + quad * 4 + r;
          o_act[row * 256 + col] = f2b(geluf(acc[fm][fn][r]));
        }
      }
    }
  }
}

// -------- MFMA K=256 GEMM: A[rows][256] @ BT[n=64][k=256], fused epilogues --------
// MODE 0: rowgrad -> dhg (row-major bf16) + dhT blocked
// MODE 1: final   -> nan0 + pf_rmsnorm + q residual -> out fp32 (merge heads)
template <int MODE>
__global__ __launch_bounds__(256) void km256(
    const u16* __restrict__ A, const u16* __restrict__ BT, long bstride,
    const u16* __restrict__ keysp, const u16* __restrict__ valsp,
    const float* __restrict__ theta, const u16* __restrict__ qp, long grow0,
    u16* __restrict__ o_dh, u16* __restrict__ o_dhT, float* __restrict__ outp) {
  __shared__ u16 As[256 * 32];
  __shared__ u16 Bs[64 * 32];
  int t = threadIdx.x;
  int wave = t >> 6, lane = t & 63;
  long rowbase = (long)blockIdx.z * S + (long)blockIdx.y * 256;
  int quad = lane >> 4, l15 = lane & 15;
  int rl = lane >> 2;
  int q = (lane & 3) ^ swz4(rl);
  const u16* Bp = BT + (long)blockIdx.z * bstride;

  f32x4 acc[4][4] = {};
  int aoff[4], boff[4];
#pragma unroll
  for (int f = 0; f < 4; f++) {
    aoff[f] = (wave * 64 + f * 16 + l15) * 32 + (quad ^ swz4(l15)) * 8;
    boff[f] = (f * 16 + l15) * 32 + (quad ^ swz4(l15)) * 8;
  }
  const u16* ga = A + (rowbase + wave * 64 + rl) * 256 + q * 8;
  const u16* gb = Bp + (size_t)(wave * 16 + rl) * 256 + q * 8;
  u16* lA0 = &As[(wave * 64) * 32];
  u16* lA1 = &As[(wave * 64 + 16) * 32];
  u16* lA2 = &As[(wave * 64 + 32) * 32];
  u16* lA3 = &As[(wave * 64 + 48) * 32];
  u16* lB  = &Bs[(wave * 16) * 32];

  for (int k0 = 0; k0 < 256; k0 += 32) {
    dma16(ga + k0, lA0);
    dma16(ga + 16 * 256 + k0, lA1);
    dma16(ga + 32 * 256 + k0, lA2);
    dma16(ga + 48 * 256 + k0, lA3);
    dma16(gb + k0, lB);
    __syncthreads();
    bf16x8 af[4], bfr[4];
#pragma unroll
    for (int f = 0; f < 4; f++) {
      af[f]  = *(const bf16x8*)&As[aoff[f]];
      bfr[f] = *(const bf16x8*)&Bs[boff[f]];
    }
#pragma unroll
    for (int i = 0; i < 4; i++)
#pragma unroll
      for (int j = 0; j < 4; j++)
        acc[i][j] = __builtin_amdgcn_mfma_f32_16x16x32_bf16(af[i], bfr[j], acc[i][j], 0, 0, 0);
    __syncthreads();
  }

#pragma unroll
  for (int fm = 0; fm < 4; fm++) {
    long sbase = rowbase + wave * 64 + fm * 16;  // group-local, 16-aligned
    if (MODE == 0) {
      f32x4 ss = acc[fm][0] * acc[fm][0] + acc[fm][1] * acc[fm][1] +
                 acc[fm][2] * acc[fm][2] + acc[fm][3] * acc[fm][3];
      f32x4 rrms, th2;
#pragma unroll
      for (int r = 0; r < 4; r++) {
        float s = rsum16(ss[r]);
        rrms[r] = rsqrtf(s * (1.f / 64) + 1e-8f);
        th2[r] = 2.f * theta[grow0 + sbase + quad * 4 + r];
      }
      f32x4 hn[4], dp[4];
      f32x4 dyp = {};
#pragma unroll
      for (int fn = 0; fn < 4; fn++) {
        int col = fn * 16 + l15;
#pragma unroll
        for (int r = 0; r < 4; r++) {
          long gr = grow0 + sbase + quad * 4 + r;
          float h = acc[fm][fn][r] * rrms[r];
          float k = b2f(keysp[gr * 64 + col]);
          float v = b2f(valsp[gr * 64 + col]);
          float d = th2[r] * (h + k - v);
          hn[fn][r] = h;
          dp[fn][r] = d;
          dyp[r] += d * h;
        }
      }
#pragma unroll
      for (int r = 0; r < 4; r++) dyp[r] = rsum16(dyp[r]);
      long s16 = sbase >> 4;
#pragma unroll
      for (int fn = 0; fn < 4; fn++) {
        int col = fn * 16 + l15;
        ushort4 ob;
#pragma unroll
        for (int r = 0; r < 4; r++) {
          float d = (dp[fn][r] - hn[fn][r] * dyp[r] * (1.f / 64)) * rrms[r];
          long row = sbase + quad * 4 + r;
          o_dh[row * 64 + col] = f2b(d);
          ((u16*)&ob)[r] = f2b(d);
        }
        *(ushort4*)&o_dhT[(s16 * 4 + fn) * 256 + l15 * 16 + quad * 4] = ob;
      }
    } else {
      f32x4 hv[4];
      f32x4 ss = {};
#pragma unroll
      for (int fn = 0; fn < 4; fn++) {
#pragma unroll
        for (int r = 0; r < 4; r++) {
          float v = nan0(acc[fm][fn][r]);
          hv[fn][r] = v;
          ss[r] += v * v;
        }
      }
      f32x4 rrms;
#pragma unroll
      for (int r = 0; r < 4; r++) {
        float s = rsum16(ss[r]);
        rrms[r] = rsqrtf(s * (1.f / 64) + 1e-8f);
      }
#pragma unroll
      for (int r = 0; r < 4; r++) {
        long gr = grow0 + sbase + quad * 4 + r;
        long bh = gr >> 11, s_ = gr & 2047;
        long b = bh >> 4, hh = bh & 15;
        size_t obase = (size_t)(b * S + s_) * D + hh * 64;
#pragma unroll
        for (int fn = 0; fn < 4; fn++) {
          int col = fn * 16 + l15;
          outp[obase + col] = hv[fn][r] * rrms[r] + b2f(qp[gr * 64 + col]);
        }
      }
    }
  }
}

// -------- g outer-product: C[m=64][n=256] = sum_s AT[m][s] * BT_[n][s] --------
// A, B both blocked-T (A: 4 tiles/s16-row, B: 16 tiles/s16-row). Split-K atomics.
__global__ __launch_bounds__(256) void kg(
    const u16* __restrict__ Ablk, const u16* __restrict__ Bblk,
    float* __restrict__ gout, long bh0) {
  int t = threadIdx.x;
  int w = t >> 6, lane = t & 63;
  int quad = lane >> 4, l15 = lane & 15;
  int z = blockIdx.y;
  int c = blockIdx.x;
  int qh = quad >> 1, ql = (quad & 1) * 8;
  f32x4 acc[4][4] = {};
  for (int step = 0; step < SCH / 32; step++) {
    long s16 = (long)z * (S / 16) + c * (SCH / 16) + step * 2 + qh;
    bf16x8 af[4], bfr[4];
#pragma unroll
    for (int f = 0; f < 4; f++)
      af[f] = *(const bf16x8*)&Ablk[(s16 * 4 + f) * 256 + l15 * 16 + ql];
#pragma unroll
    for (int f = 0; f < 4; f++)
      bfr[f] = *(const bf16x8*)&Bblk[(s16 * 16 + w * 4 + f) * 256 + l15 * 16 + ql];
#pragma unroll
    for (int i = 0; i < 4; i++)
#pragma unroll
      for (int j = 0; j < 4; j++)
        acc[i][j] = __builtin_amdgcn_mfma_f32_16x16x32_bf16(af[i], bfr[j], acc[i][j], 0, 0, 0);
  }
  float* gp_ = gout + (bh0 + z) * 16384;
#pragma unroll
  for (int i = 0; i < 4; i++)
#pragma unroll
    for (int j = 0; j < 4; j++) {
      int n = w * 64 + j * 16 + l15;
#pragma unroll
      for (int r = 0; r < 4; r++) {
        int m = i * 16 + quad * 4 + r;
        atomicAdd(&gp_[(size_t)m * 256 + n], acc[i][j][r]);
      }
    }
}

// ---------------- zero-fill ----------------
__global__ void k_zero(float* __restrict__ p, long n) {
  long i = (long)blockIdx.x * 256 + threadIdx.x;
  if (i < n) p[i] = 0.f;
}

// ---------------- grad-norm clip coefficient per bh ----------------
__global__ void k_clip(const float* __restrict__ g0, const float* __restrict__ g1,
                       float* __restrict__ coef) {
  int bh = blockIdx.x, t = threadIdx.x;
  const float* p0 = g0 + (long)bh * 16384;
  const float* p1 = g1 + (long)bh * 16384;
  float s = 0.f;
  for (int i = t; i < 16384; i += 256) {
    float a = p0[i]; s += a * a;
    float b = p1[i]; s += b * b;
  }
  s = wsum(s);
  __shared__ float sh[4];
  int w = t >> 6, lane = t & 63;
  if (lane == 0) sh[w] = s;
  __syncthreads();
  if (t == 0) {
    float tot = sh[0] + sh[1] + sh[2] + sh[3];
    float c = 10.f / (sqrtf(tot) + 1e-6f);
    coef[bh] = fminf(c, 1.f);
  }
}

// ---- weight update -> transposed bf16 fast weights for retrieve MFMA ----
// nW0T[bh][i][k] = guard((1-a)W0[k][i] - c*g0t[bh][k*256+i])
// nW1T[bh][o][i] = guard((1-a)W1[i][o] - c*g1t[bh][o*256+i])
__global__ void k_updT(const float* __restrict__ W0, const float* __restrict__ W1,
                       const float* __restrict__ g0t, const float* __restrict__ g1t,
                       const float* __restrict__ amean, const float* __restrict__ coef,
                       u16* __restrict__ nW0T, u16* __restrict__ nW1T) {
  long i = (long)blockIdx.x * 256 + threadIdx.x;  // 2 * BH * 16384
  int half = (int)(i >> 21);
  long j = i & ((1L << 21) - 1);
  int bh = (int)(j >> 14);
  int idx = (int)(j & 16383);
  float a = 1.f - amean[bh], cf = coef[bh];
  if (half == 0) {
    int k = idx & 63, ii = idx >> 6;
    float w = W0[k * 256 + ii];
    float nw = a * w - cf * g0t[(long)bh * 16384 + k * 256 + ii];
    if (!finitef(nw)) nw = w;
    nW0T[j] = f2b(nw);
  } else {
    int ii = idx & 255, o = idx >> 8;
    float w = W1[ii * 64 + o];
    float nw = a * w - cf * g1t[(long)bh * 16384 + idx];
    if (!finitef(nw)) nw = w;
    nW1T[j] = f2b(nw);
  }
}

extern "C" void kernel_launch(void* const* d_in, const int* in_sizes, int n_in,
                              void* d_out, int out_size, void* d_ws, size_t ws_size,
                              hipStream_t stream) {
  const float* x   = (const float*)d_in[0];
  const float* W_K = (const float*)d_in[1];
  const float* W_V = (const float*)d_in[2];
  const float* W_Q = (const float*)d_in[3];
  const float* mW0 = (const float*)d_in[4];
  const float* mW1 = (const float*)d_in[5];
  const float* knw = (const float*)d_in[6];
  const float* qnw = (const float*)d_in[7];
  const float* snw = (const float*)d_in[8];
  const float* rnw = (const float*)d_in[9];
  const float* aw  = (const float*)d_in[10];
  const float* ab  = (const float*)d_in[11];
  const float* tw  = (const float*)d_in[12];
  const float* tb  = (const float*)d_in[13];
  float* out = (float*)d_out;
  (void)ws_size; (void)in_sizes; (void)n_in; (void)out_size;

  // workspace carve-up (~204 MB)
  char* w = (char*)d_ws;
  auto alloc = [&](size_t bytes) {
    char* p = w;
    w += (bytes + 255) / 256 * 256;
    return p;
  };
  float* rinv   = (float*)alloc((size_t)BS * 4);
  u16*   xs     = (u16*)alloc((size_t)BS * D * 2);        // 32 MB
  u16*   WTb    = (u16*)alloc((size_t)3 * D * D * 2);     // 6 MB
  u16*   keys   = (u16*)alloc(NR * 64 * 2);               // 32 MB (reused as q)
  u16*   vals   = (u16*)alloc(NR * 64 * 2);               // 32 MB
  float* alpha  = (float*)alloc(NR * 4);                  // 1 MB
  float* theta  = (float*)alloc(NR * 4);                  // 1 MB
  float* amean  = (float*)alloc(BH * 4);
  float* coef   = (float*)alloc(BH * 4);
  u16*   W0T    = (u16*)alloc(16384 * 2);
  u16*   W1b    = (u16*)alloc(16384 * 2);
  u16*   W1T    = (u16*)alloc(16384 * 2);
  u16*   act0   = (u16*)alloc((size_t)GR * 256 * 2);      // 16 MB group
  u16*   gpb    = (u16*)alloc((size_t)GR * 256 * 2);      // 16 MB group
  u16*   act0T  = (u16*)alloc((size_t)GR * 256 * 2);      // 16 MB group (blocked)
  u16*   dhg    = (u16*)alloc((size_t)GR * 64 * 2);       // 4 MB group
  u16*   dhT    = (u16*)alloc((size_t)GR * 64 * 2);       // 4 MB group (blocked)
  u16*   dh0T   = (u16*)alloc((size_t)GR * 256 * 2);      // 16 MB group (blocked)
  u16*   keysTb = (u16*)alloc((size_t)GR * 64 * 2);       // 4 MB group (blocked)
  float* g0t    = (float*)alloc((size_t)BH * 16384 * 4);  // 8 MB (g1t adjacent)
  float* g1t    = (float*)alloc((size_t)BH * 16384 * 4);  // 8 MB
  u16*   nW0T   = (u16*)alloc((size_t)BH * 16384 * 2);    // 4 MB
  u16*   nW1T   = (u16*)alloc((size_t)BH * 16384 * 2);    // 4 MB

  // ---- store path ----
  k_xnorm<true><<<BS / 4, 256, 0, stream>>>(x, snw, rinv, xs);
  k_wtrans<<<dim3(16, 16, 3), 256, 0, stream>>>(W_K, W_V, W_Q, WTb);
  k_proj_mfma<true><<<dim3(8, 128), 256, 0, stream>>>(xs, WTb, knw, keys);
  k_proj_mfma<false><<<dim3(8, 128), 256, 0, stream>>>(xs, WTb + (size_t)D * D, nullptr, vals);
  k_ate<<<BS / 64, 256, 0, stream>>>(x, rinv, snw, aw, ab, tw, tb, alpha, theta);
  k_mean<<<BH, 256, 0, stream>>>(alpha, amean);
  k_wsmall<<<dim3(64, 3), 256, 0, stream>>>(mW0, mW1, W0T, W1b, W1T);
  k_zero<<<(int)((2L * BH * 16384 + 255) / 256), 256, 0, stream>>>(g0t, 2L * BH * 16384);

  // ---- memory grad (8 groups of 16 bh) ----
  for (int g = 0; g < NG; g++) {
    long bh0 = (long)g * GB;
    long grow0 = bh0 * S;
    const u16* keys_g = keys + grow0 * 64;
    k_keysT<<<GR / 16, 256, 0, stream>>>(keys_g, keysTb);
    km64<0><<<dim3(2, GR / 128, 1), 256, 0, stream>>>(
        keys_g, W0T, 0, nullptr, act0, gpb, act0T);
    km256<0><<<dim3(1, GR / 256, 1), 256, 0, stream>>>(
        act0, W1T, 0, keys, vals, theta, nullptr, grow0, dhg, dhT, nullptr);
    km64<1><<<dim3(2, GR / 128, 1), 256, 0, stream>>>(
        dhg, W1b, 0, gpb, nullptr, nullptr, dh0T);
    kg<<<dim3(NSPL, GB), 256, 0, stream>>>(dhT, act0T, g1t, bh0);    // g1t[o][i]
    kg<<<dim3(NSPL, GB), 256, 0, stream>>>(keysTb, dh0T, g0t, bh0);  // g0t[k][i]
  }
  k_clip<<<BH, 256, 0, stream>>>(g0t, g1t, coef);
  k_updT<<<(int)(2L * BH * 16384 / 256), 256, 0, stream>>>(
      mW0, mW1, g0t, g1t, amean, coef, nW0T, nW1T);

  // ---- retrieve ----
  k_xnorm<false><<<BS / 4, 256, 0, stream>>>(x, rnw, rinv, xs);
  u16* q = keys;
  k_proj_mfma<true><<<dim3(8, 128), 256, 0, stream>>>(xs, WTb + (size_t)2 * D * D, qnw, q);
  for (int g = 0; g < NG; g++) {
    long bh0 = (long)g * GB;
    long grow0 = bh0 * S;
    km64<2><<<dim3(2, S / 128, GB), 256, 0, stream>>>(
        q + grow0 * 64, nW0T + bh0 * 16384, 16384, nullptr, act0, nullptr, nullptr);
    km256<1><<<dim3(1, S / 256, GB), 256, 0, stream>>>(
        act0, nW1T + bh0 * 16384, 16384, nullptr, nullptr, nullptr, q, grow0,
        nullptr, nullptr, out);
  }
}